// Round 2
// baseline (407.618 us; speedup 1.0000x reference)
//
#include <hip/hip_runtime.h>
#include <hip/hip_bf16.h>
#include <math.h>

// MoE router (DeepSeek-V3 biased top-k gating), T=32768 tokens, E=256 experts, K=8.
// hidden_states (d_in[0]) is NOT used by the reference computation.
// Outputs (flat float32): scores[T*K], idx[T*K], expert_counts[E], offsets[T*K].

constexpr int E = 256;           // num experts
constexpr int K = 8;             // top_k
constexpr int TOK_PER_CHUNK = 128;
constexpr int CHUNK_ELEMS = TOK_PER_CHUNK * K;   // 1024

// ---------------------------------------------------------------------------
// Kernel 1: per-token sigmoid + biased top-k. One wave (64 lanes) per token;
// each lane owns 4 consecutive experts (float4 load). 8 rounds of wave argmax
// with tie-break on lower index (matches jax.lax.top_k stability).
// ---------------------------------------------------------------------------
__global__ __launch_bounds__(256) void topk_kernel(
    const float* __restrict__ logits,
    const float* __restrict__ bias,
    float* __restrict__ out_scores,  // [T*K]
    float* __restrict__ out_idx,     // [T*K] (index values stored as float)
    int*   __restrict__ ws_idx,      // [T*K] int scratch for later passes
    int T)
{
    const int wave = (blockIdx.x * blockDim.x + threadIdx.x) >> 6;
    const int lane = threadIdx.x & 63;
    if (wave >= T) return;

    const float4 x = reinterpret_cast<const float4*>(logits + (size_t)wave * E)[lane];
    const float4 b = reinterpret_cast<const float4*>(bias)[lane];

    // sigmoid (original scores) and selection scores
    float s0 = 1.f / (1.f + expf(-x.x));
    float s1 = 1.f / (1.f + expf(-x.y));
    float s2 = 1.f / (1.f + expf(-x.z));
    float s3 = 1.f / (1.f + expf(-x.w));
    float sel0 = s0 + b.x;
    float sel1 = s1 + b.y;
    float sel2 = s2 + b.z;
    float sel3 = s3 + b.w;

    float sc[K];
    int   id[K];
    float sum = 0.f;

    #pragma unroll
    for (int r = 0; r < K; ++r) {
        // local argmax among this lane's 4 (lowest index wins ties)
        float bv = sel0; int bi = lane * 4;
        if (sel1 > bv) { bv = sel1; bi = lane * 4 + 1; }
        if (sel2 > bv) { bv = sel2; bi = lane * 4 + 2; }
        if (sel3 > bv) { bv = sel3; bi = lane * 4 + 3; }
        // wave-wide argmax butterfly
        #pragma unroll
        for (int off = 32; off; off >>= 1) {
            float ov = __shfl_xor(bv, off, 64);
            int   oi = __shfl_xor(bi, off, 64);
            if (ov > bv || (ov == bv && oi < bi)) { bv = ov; bi = oi; }
        }
        // winner (bi) is wave-uniform; fetch its ORIGINAL sigmoid score
        const int j = bi & 3, src = bi >> 2;
        float cand = (j == 0) ? s0 : (j == 1) ? s1 : (j == 2) ? s2 : s3;
        float sv = __shfl(cand, src, 64);
        sc[r] = sv; id[r] = bi; sum += sv;
        // knock out the winner
        if (lane == src) {
            if      (j == 0) sel0 = -INFINITY;
            else if (j == 1) sel1 = -INFINITY;
            else if (j == 2) sel2 = -INFINITY;
            else             sel3 = -INFINITY;
        }
    }

    if (lane == 0) {
        const size_t o = (size_t)wave * K;
        float4 a = make_float4(sc[0] / sum, sc[1] / sum, sc[2] / sum, sc[3] / sum);
        float4 c = make_float4(sc[4] / sum, sc[5] / sum, sc[6] / sum, sc[7] / sum);
        *reinterpret_cast<float4*>(out_scores + o)     = a;
        *reinterpret_cast<float4*>(out_scores + o + 4) = c;
        float4 fi0 = make_float4((float)id[0], (float)id[1], (float)id[2], (float)id[3]);
        float4 fi1 = make_float4((float)id[4], (float)id[5], (float)id[6], (float)id[7]);
        *reinterpret_cast<float4*>(out_idx + o)     = fi0;
        *reinterpret_cast<float4*>(out_idx + o + 4) = fi1;
        int4 w0 = make_int4(id[0], id[1], id[2], id[3]);
        int4 w1 = make_int4(id[4], id[5], id[6], id[7]);
        *reinterpret_cast<int4*>(ws_idx + o)     = w0;
        *reinterpret_cast<int4*>(ws_idx + o + 4) = w1;
    }
}

// ---------------------------------------------------------------------------
// Kernel 2: per-chunk histogram (chunk = 128 tokens = 1024 assignments).
// ---------------------------------------------------------------------------
__global__ __launch_bounds__(256) void hist_kernel(
    const int* __restrict__ ws_idx,
    int* __restrict__ cnt,           // [nchunk][E]
    int total)                        // T*K
{
    __shared__ int h[E];
    h[threadIdx.x] = 0;
    __syncthreads();
    const int base = blockIdx.x * CHUNK_ELEMS;
    const int n = min(CHUNK_ELEMS, total - base);
    for (int p = threadIdx.x; p < n; p += 256)
        atomicAdd(&h[ws_idx[base + p]], 1);
    __syncthreads();
    cnt[blockIdx.x * E + threadIdx.x] = h[threadIdx.x];
}

// ---------------------------------------------------------------------------
// Kernel 3: per-expert exclusive scan over chunk counts (one block per expert,
// thread b = chunk b; Hillis-Steele in LDS). Also emits expert_counts.
// ---------------------------------------------------------------------------
__global__ __launch_bounds__(256) void scan_kernel(
    const int* __restrict__ cnt,     // [nchunk][E]
    int* __restrict__ baseoff,       // [nchunk][E] exclusive prefix
    float* __restrict__ out_counts,  // [E] as float
    int nchunk)
{
    const int e = blockIdx.x;
    const int b = threadIdx.x;
    __shared__ int v[256];
    const int c = (b < nchunk) ? cnt[b * E + e] : 0;
    v[b] = c;
    __syncthreads();
    #pragma unroll
    for (int off = 1; off < 256; off <<= 1) {
        int t = (b >= off) ? v[b - off] : 0;
        __syncthreads();
        v[b] += t;
        __syncthreads();
    }
    const int incl = v[b];
    if (b < nchunk) baseoff[b * E + e] = incl - c;
    if (b == 255) out_counts[e] = (float)incl;
}

// ---------------------------------------------------------------------------
// Kernel 4: within-chunk ordered rank. Thread e walks the chunk's assignments
// in flattened order (LDS broadcast); on match emits base + running count.
// Experts are distinct within a token, so this reproduces the reference's
// flattened row-major exclusive running count exactly.
// ---------------------------------------------------------------------------
__global__ __launch_bounds__(256) void offs_kernel(
    const int* __restrict__ ws_idx,
    const int* __restrict__ baseoff, // [nchunk][E]
    float* __restrict__ out_off,     // [T*K] as float
    int total)
{
    __shared__ int sidx[CHUNK_ELEMS];
    const int base = blockIdx.x * CHUNK_ELEMS;
    const int n = min(CHUNK_ELEMS, total - base);
    for (int p = threadIdx.x; p < n; p += 256)
        sidx[p] = ws_idx[base + p];
    const int e = threadIdx.x;
    int c = baseoff[blockIdx.x * E + e];
    __syncthreads();
    for (int p = 0; p < n; ++p) {
        int v = sidx[p];             // same address for all threads -> broadcast
        if (v == e) { out_off[base + p] = (float)c; ++c; }
    }
}

// ---------------------------------------------------------------------------
extern "C" void kernel_launch(void* const* d_in, const int* in_sizes, int n_in,
                              void* d_out, int out_size, void* d_ws, size_t ws_size,
                              hipStream_t stream) {
    const float* logits = (const float*)d_in[1];          // [T, E] fp32
    const float* bias   = (const float*)d_in[2];          // [E] fp32
    const int T = in_sizes[1] / E;                        // 32768
    const int total = T * K;
    const int nchunk = (T + TOK_PER_CHUNK - 1) / TOK_PER_CHUNK;  // 256

    float* out        = (float*)d_out;
    float* out_scores = out;
    float* out_idx    = out + (size_t)total;
    float* out_counts = out + 2 * (size_t)total;
    float* out_off    = out_counts + E;

    int* ws_idx  = (int*)d_ws;                 // total ints
    int* cnt     = ws_idx + total;             // nchunk*E ints
    int* baseoff = cnt + nchunk * E;           // nchunk*E ints

    topk_kernel<<<(T + 3) / 4, 256, 0, stream>>>(logits, bias, out_scores, out_idx, ws_idx, T);
    hist_kernel<<<nchunk, 256, 0, stream>>>(ws_idx, cnt, total);
    scan_kernel<<<E, 256, 0, stream>>>(cnt, baseoff, out_counts, nchunk);
    offs_kernel<<<nchunk, 256, 0, stream>>>(ws_idx, baseoff, out_off, total);
}

// Round 6
// 385.592 us; speedup vs baseline: 1.0571x; 1.0571x over previous
//
#include <hip/hip_runtime.h>
#include <hip/hip_bf16.h>
#include <math.h>

// MoE router (DeepSeek-V3 biased top-k gating), T=32768, E=256, K=8.
// hidden_states (d_in[0]) is unused by the reference math.
// Outputs (flat float32): scores[T*K], idx[T*K], expert_counts[E], offsets[T*K].
//
// Structure (3 kernels):
//  K1 topk_hist: 1 wave/token, 16 tokens/block (block==chunk). Biased top-k via
//     wave argmax butterfly; per-chunk histogram in LDS -> cnt[chunk][E].
//  K2 scan: 1 block/expert, exclusive scan of cnt over 2048 chunks -> baseoff,
//     plus expert_counts.
//  K3 offs: 1 block/chunk, 128-entry ordered walk -> flattened-order ranks.

constexpr int E = 256;
constexpr int K = 8;
constexpr int TOK_PER_BLK = 16;                  // tokens per chunk/block
constexpr int CHUNK_ELEMS = TOK_PER_BLK * K;     // 128
constexpr int MAX_CHUNKS = 2048;                 // scan kernel capacity (T<=32768)

// ---------------------------------------------------------------------------
// K1: top-k + per-chunk histogram. 1024 threads = 16 waves = 16 tokens.
// ---------------------------------------------------------------------------
__global__ __launch_bounds__(1024) void topk_hist_kernel(
    const float* __restrict__ logits,
    const float* __restrict__ bias,
    float* __restrict__ out_scores,  // [T*K]
    float* __restrict__ out_idx,     // [T*K] (float-encoded ints)
    int*   __restrict__ ws_idx,      // [T*K]
    int*   __restrict__ cnt,         // [nchunk][E]
    int T)
{
    __shared__ int h[E];
    const int tid = threadIdx.x;
    if (tid < E) h[tid] = 0;
    __syncthreads();

    const int wid  = tid >> 6;
    const int lane = tid & 63;
    const int token = blockIdx.x * TOK_PER_BLK + wid;
    const bool active = token < T;

    float sc[K];
    int   id[K];
    float sum = 0.f;

    if (active) {
        const float4 x = reinterpret_cast<const float4*>(logits + (size_t)token * E)[lane];
        const float4 b = reinterpret_cast<const float4*>(bias)[lane];
        float s0 = 1.f / (1.f + __expf(-x.x));
        float s1 = 1.f / (1.f + __expf(-x.y));
        float s2 = 1.f / (1.f + __expf(-x.z));
        float s3 = 1.f / (1.f + __expf(-x.w));
        float sel0 = s0 + b.x, sel1 = s1 + b.y, sel2 = s2 + b.z, sel3 = s3 + b.w;

        #pragma unroll
        for (int r = 0; r < K; ++r) {
            // local argmax among this lane's 4 (lowest index wins ties)
            float bv = sel0; int bi = lane * 4;
            if (sel1 > bv) { bv = sel1; bi = lane * 4 + 1; }
            if (sel2 > bv) { bv = sel2; bi = lane * 4 + 2; }
            if (sel3 > bv) { bv = sel3; bi = lane * 4 + 3; }
            // wave-wide argmax butterfly (tie-break: lower index)
            #pragma unroll
            for (int off = 32; off; off >>= 1) {
                float ov = __shfl_xor(bv, off, 64);
                int   oi = __shfl_xor(bi, off, 64);
                if (ov > bv || (ov == bv && oi < bi)) { bv = ov; bi = oi; }
            }
            const int j = bi & 3, src = bi >> 2;
            float cand = (j == 0) ? s0 : (j == 1) ? s1 : (j == 2) ? s2 : s3;
            float sv = __shfl(cand, src, 64);
            sc[r] = sv; id[r] = bi; sum += sv;
            if (lane == src) {
                if      (j == 0) sel0 = -INFINITY;
                else if (j == 1) sel1 = -INFINITY;
                else if (j == 2) sel2 = -INFINITY;
                else             sel3 = -INFINITY;
            }
        }

        // histogram: lanes 0..7 contribute one expert each (values wave-uniform)
        if (lane < 8) {
            int v = id[0];
            if (lane == 1) v = id[1];
            if (lane == 2) v = id[2];
            if (lane == 3) v = id[3];
            if (lane == 4) v = id[4];
            if (lane == 5) v = id[5];
            if (lane == 6) v = id[6];
            if (lane == 7) v = id[7];
            atomicAdd(&h[v], 1);
        }

        if (lane == 0) {
            const size_t o = (size_t)token * K;
            float inv = 1.f / sum;
            float4 a = make_float4(sc[0] * inv, sc[1] * inv, sc[2] * inv, sc[3] * inv);
            float4 c = make_float4(sc[4] * inv, sc[5] * inv, sc[6] * inv, sc[7] * inv);
            *reinterpret_cast<float4*>(out_scores + o)     = a;
            *reinterpret_cast<float4*>(out_scores + o + 4) = c;
            float4 f0 = make_float4((float)id[0], (float)id[1], (float)id[2], (float)id[3]);
            float4 f1 = make_float4((float)id[4], (float)id[5], (float)id[6], (float)id[7]);
            *reinterpret_cast<float4*>(out_idx + o)     = f0;
            *reinterpret_cast<float4*>(out_idx + o + 4) = f1;
            int4 w0 = make_int4(id[0], id[1], id[2], id[3]);
            int4 w1 = make_int4(id[4], id[5], id[6], id[7]);
            *reinterpret_cast<int4*>(ws_idx + o)     = w0;
            *reinterpret_cast<int4*>(ws_idx + o + 4) = w1;
        }
    }

    __syncthreads();
    if (tid < E) cnt[(size_t)blockIdx.x * E + tid] = h[tid];
}

// ---------------------------------------------------------------------------
// K2: per-expert exclusive scan over chunk counts. Block e: 256 threads x 8
// chunks each (capacity 2048 chunks). Emits baseoff[chunk][E] + counts[E].
// ---------------------------------------------------------------------------
__global__ __launch_bounds__(256) void scan_kernel(
    const int* __restrict__ cnt,     // [nchunk][E]
    int* __restrict__ baseoff,       // [nchunk][E]
    float* __restrict__ out_counts,  // [E]
    int nchunk)
{
    const int e = blockIdx.x;
    const int b = threadIdx.x;

    int lps[8];            // exclusive within-thread prefix
    int lp = 0;
    #pragma unroll
    for (int j = 0; j < 8; ++j) {
        const int c = 8 * b + j;
        int v = (c < nchunk) ? cnt[(size_t)c * E + e] : 0;
        lps[j] = lp;
        lp += v;
    }

    __shared__ int s[256];
    s[b] = lp;
    __syncthreads();
    #pragma unroll
    for (int off = 1; off < 256; off <<= 1) {
        int t = (b >= off) ? s[b - off] : 0;
        __syncthreads();
        s[b] += t;
        __syncthreads();
    }
    const int excl = s[b] - lp;      // exclusive across threads
    #pragma unroll
    for (int j = 0; j < 8; ++j) {
        const int c = 8 * b + j;
        if (c < nchunk) baseoff[(size_t)c * E + e] = excl + lps[j];
    }
    if (b == 255) out_counts[e] = (float)s[255];
}

// ---------------------------------------------------------------------------
// K3: within-chunk ordered rank (128 entries). Thread e walks in flattened
// order via LDS broadcast reads; emits base + running count on match.
// ---------------------------------------------------------------------------
__global__ __launch_bounds__(256) void offs_kernel(
    const int* __restrict__ ws_idx,
    const int* __restrict__ baseoff, // [nchunk][E]
    float* __restrict__ out_off,     // [T*K]
    int total)
{
    __shared__ int sidx[CHUNK_ELEMS];
    const int base = blockIdx.x * CHUNK_ELEMS;
    const int n = min(CHUNK_ELEMS, total - base);
    if ((int)threadIdx.x < n) sidx[threadIdx.x] = ws_idx[base + threadIdx.x];
    const int e = threadIdx.x;
    int c = baseoff[(size_t)blockIdx.x * E + e];   // coalesced
    __syncthreads();
    for (int p = 0; p < n; ++p) {
        if (sidx[p] == e) { out_off[base + p] = (float)c; ++c; }
    }
}

// ---------------------------------------------------------------------------
extern "C" void kernel_launch(void* const* d_in, const int* in_sizes, int n_in,
                              void* d_out, int out_size, void* d_ws, size_t ws_size,
                              hipStream_t stream) {
    const float* logits = (const float*)d_in[1];          // [T, E] fp32
    const float* bias   = (const float*)d_in[2];          // [E] fp32
    const int T = in_sizes[1] / E;                        // 32768
    const int total = T * K;
    const int nchunk = (T + TOK_PER_BLK - 1) / TOK_PER_BLK;  // 2048
    (void)MAX_CHUNKS;

    float* out        = (float*)d_out;
    float* out_scores = out;
    float* out_idx    = out + (size_t)total;
    float* out_counts = out + 2 * (size_t)total;
    float* out_off    = out_counts + E;

    int* ws_idx  = (int*)d_ws;                    // total ints
    int* cnt     = ws_idx + total;                // nchunk*E ints
    int* baseoff = cnt + (size_t)nchunk * E;      // nchunk*E ints

    topk_hist_kernel<<<nchunk, 1024, 0, stream>>>(logits, bias, out_scores, out_idx,
                                                  ws_idx, cnt, T);
    scan_kernel<<<E, 256, 0, stream>>>(cnt, baseoff, out_counts, nchunk);
    offs_kernel<<<nchunk, 256, 0, stream>>>(ws_idx, baseoff, out_off, total);
}